// Round 2
// baseline (697.954 us; speedup 1.0000x reference)
//
#include <hip/hip_runtime.h>
#include <math.h>

#define H 4096

__device__ __forceinline__ float sigmoidf_(float x) {
    return 1.0f / (1.0f + __expf(-x));
}

// Init: seed the 12 y1 accumulators with b1, zero the completion counter.
// Needed every call: d_ws is poisoned 0xAA once and never re-zeroed between
// graph replays.
__global__ void init_kernel(const float* __restrict__ b1, float* __restrict__ ws) {
    const int t = threadIdx.x;
    if (t < 12) ws[t] = b1[t];
    else if (t == 12) ((unsigned int*)ws)[12] = 0u;
}

// Fused: gates GEMV -> h_new/c_new -> atomic partial of y1 = w1@h_new (+b1 via
// init) -> last block computes the tiny 12->8->4 tail and writes out[0..4).
__global__ __launch_bounds__(256) void lstm_fused_kernel(
    const float* __restrict__ x,      // [4]
    const float* __restrict__ h,      // [H]
    const float* __restrict__ c,      // [H]
    const float* __restrict__ W_ih,   // [4H, 4]
    const float* __restrict__ W_hh,   // [4H, H]
    const float* __restrict__ b_ih,   // [4H]
    const float* __restrict__ b_hh,   // [4H]
    const float* __restrict__ w1,     // [12, H]
    const float* __restrict__ w2, const float* __restrict__ b2,  // [8,12],[8]
    const float* __restrict__ w3, const float* __restrict__ b3,  // [4,8],[4]
    float* __restrict__ out,          // [0..4) y, [4..4+H) h_new, [4+H..4+2H) c_new
    float* __restrict__ ws)           // [0..12) y1 acc, [12] counter
{
    const int j    = blockIdx.x;           // 0..H-1
    const int wave = threadIdx.x >> 6;     // gate index i,f,g,o
    const int lane = threadIdx.x & 63;
    const int row  = wave * H + j;

    // Prefetch w1 column j early (thread 0 only) so the 12 strided loads'
    // latency hides under the main streaming loop.
    float w1c[12];
    if (threadIdx.x == 0) {
#pragma unroll
        for (int w = 0; w < 12; ++w) w1c[w] = w1[w * H + j];
    }

    const float4* __restrict__ Wrow = (const float4*)(W_hh + (size_t)row * H);
    const float4* __restrict__ hv   = (const float4*)h;

    float acc = 0.0f;
#pragma unroll
    for (int it = 0; it < 16; ++it) {
        const int idx = lane + it * 64;    // 0..1023 float4's
        float4 w4 = Wrow[idx];
        float4 h4 = hv[idx];
        acc += w4.x * h4.x + w4.y * h4.y + w4.z * h4.z + w4.w * h4.w;
    }
#pragma unroll
    for (int off = 32; off > 0; off >>= 1)
        acc += __shfl_down(acc, off, 64);

    __shared__ float gate[4];
    if (lane == 0) {
        float g = acc + b_ih[row] + b_hh[row];
        const float4 wi = ((const float4*)W_ih)[row];
        g += wi.x * x[0] + wi.y * x[1] + wi.z * x[2] + wi.w * x[3];
        gate[wave] = g;
    }
    __syncthreads();

    if (threadIdx.x == 0) {
        const float cn = sigmoidf_(gate[1]) * c[j] + sigmoidf_(gate[0]) * tanhf(gate[2]);
        const float hn = sigmoidf_(gate[3]) * tanhf(cn);
        out[4 + j]     = hn;
        out[4 + H + j] = cn;

        // y1 partials (device-scope atomics, coherent across XCDs)
#pragma unroll
        for (int w = 0; w < 12; ++w) atomicAdd(&ws[w], w1c[w] * hn);
        __threadfence();
        const unsigned int old = atomicAdd((unsigned int*)ws + 12, 1u);
        if (old == (unsigned int)(gridDim.x - 1)) {
            // All blocks' y1 atomics are visible (their fences ordered them
            // before their counter adds). Tail MLP, scalar on one thread.
            float y1[12];
#pragma unroll
            for (int w = 0; w < 12; ++w)
                y1[w] = fmaxf(atomicAdd(&ws[w], 0.0f), 0.0f);  // coherent read
            float y2[8];
#pragma unroll
            for (int r = 0; r < 8; ++r) {
                float a = b2[r];
#pragma unroll
                for (int k = 0; k < 12; ++k) a += w2[r * 12 + k] * y1[k];
                y2[r] = fmaxf(a, 0.0f);
            }
#pragma unroll
            for (int r = 0; r < 4; ++r) {
                float a = b3[r];
#pragma unroll
                for (int k = 0; k < 8; ++k) a += w3[r * 8 + k] * y2[k];
                out[r] = a;
            }
        }
    }
}

extern "C" void kernel_launch(void* const* d_in, const int* in_sizes, int n_in,
                              void* d_out, int out_size, void* d_ws, size_t ws_size,
                              hipStream_t stream) {
    const float* x    = (const float*)d_in[0];
    const float* h    = (const float*)d_in[1];
    const float* c    = (const float*)d_in[2];
    const float* W_ih = (const float*)d_in[3];
    const float* W_hh = (const float*)d_in[4];
    const float* b_ih = (const float*)d_in[5];
    const float* b_hh = (const float*)d_in[6];
    const float* w1   = (const float*)d_in[7];
    const float* b1   = (const float*)d_in[8];
    const float* w2   = (const float*)d_in[9];
    const float* b2   = (const float*)d_in[10];
    const float* w3   = (const float*)d_in[11];
    const float* b3   = (const float*)d_in[12];
    float* out = (float*)d_out;
    float* ws  = (float*)d_ws;

    init_kernel<<<1, 64, 0, stream>>>(b1, ws);
    lstm_fused_kernel<<<H, 256, 0, stream>>>(x, h, c, W_ih, W_hh, b_ih, b_hh,
                                             w1, w2, b2, w3, b3, out, ws);
}

// Round 3
// 52.704 us; speedup vs baseline: 13.2429x; 13.2429x over previous
//
#include <hip/hip_runtime.h>
#include <math.h>

#define H 4096

__device__ __forceinline__ float sigmoidf_(float x) {
    return 1.0f / (1.0f + __expf(-x));
}

// Kernel 1: gates = W_ih@x + b_ih + W_hh@h + b_hh ; then c_new/h_new.
// One block per output element j (H blocks). 4 waves: wave g computes the
// dot of W_hh row (g*H + j) with h (4096 elements, float4 loads, wave-wide).
// Block 0 additionally zeroes the 13 workspace words used by kernel 2
// (visible to kernel 2 via kernel-completion flush + stream order).
__global__ __launch_bounds__(256) void lstm_step_kernel(
    const float* __restrict__ x,      // [4]
    const float* __restrict__ h,      // [H]
    const float* __restrict__ c,      // [H]
    const float* __restrict__ W_ih,   // [4H, 4]
    const float* __restrict__ W_hh,   // [4H, H]
    const float* __restrict__ b_ih,   // [4H]
    const float* __restrict__ b_hh,   // [4H]
    float* __restrict__ out,          // [0..4) y, [4..4+H) h_new, [4+H..4+2H) c_new
    float* __restrict__ ws)           // [0..12) y1 acc, [12] counter
{
    const int j    = blockIdx.x;           // 0..H-1
    const int wave = threadIdx.x >> 6;     // gate index i,f,g,o
    const int lane = threadIdx.x & 63;
    const int row  = wave * H + j;

    if (j == 0 && threadIdx.x == 63) {
#pragma unroll
        for (int w = 0; w < 12; ++w) ws[w] = 0.0f;
        ((unsigned int*)ws)[12] = 0u;
    }

    const float4* __restrict__ Wrow = (const float4*)(W_hh + (size_t)row * H);
    const float4* __restrict__ hv   = (const float4*)h;

    float acc = 0.0f;
#pragma unroll
    for (int it = 0; it < 16; ++it) {
        const int idx = lane + it * 64;    // 0..1023 float4's
        float4 w4 = Wrow[idx];
        float4 h4 = hv[idx];
        acc += w4.x * h4.x + w4.y * h4.y + w4.z * h4.z + w4.w * h4.w;
    }
#pragma unroll
    for (int off = 32; off > 0; off >>= 1)
        acc += __shfl_down(acc, off, 64);

    __shared__ float gate[4];
    if (lane == 0) {
        float g = acc + b_ih[row] + b_hh[row];
        const float4 wi = ((const float4*)W_ih)[row];
        g += wi.x * x[0] + wi.y * x[1] + wi.z * x[2] + wi.w * x[3];
        gate[wave] = g;
    }
    __syncthreads();

    if (threadIdx.x == 0) {
        const float cn = sigmoidf_(gate[1]) * c[j] + sigmoidf_(gate[0]) * tanhf(gate[2]);
        const float hn = sigmoidf_(gate[3]) * tanhf(cn);
        out[4 + j]     = hn;
        out[4 + H + j] = cn;
    }
}

// Kernel 2: MLP head. 12 blocks, one per w1 row. Block-reduce the dot,
// atomically publish y1[row]; the last-arriving block runs the 12->8->4 tail.
__global__ __launch_bounds__(256) void mlp_head_kernel(
    const float* __restrict__ w1, const float* __restrict__ b1,  // [12,H],[12]
    const float* __restrict__ w2, const float* __restrict__ b2,  // [8,12],[8]
    const float* __restrict__ w3, const float* __restrict__ b3,  // [4,8],[4]
    float* __restrict__ out,          // h_new at out+4
    float* __restrict__ ws)           // [0..12) y1, [12] counter (zeroed by k1)
{
    const float* __restrict__ h_new = out + 4;
    const int row  = blockIdx.x;          // 0..11
    const int t    = threadIdx.x;         // 0..255
    const int wave = t >> 6;
    const int lane = t & 63;

    const float4* __restrict__ wr = (const float4*)(w1 + (size_t)row * H);
    const float4* __restrict__ hv = (const float4*)h_new;

    float acc = 0.0f;
#pragma unroll
    for (int k = 0; k < 4; ++k) {
        const int idx = t + k * 256;      // 0..1023 float4's
        float4 a = wr[idx];
        float4 b = hv[idx];
        acc += a.x * b.x + a.y * b.y + a.z * b.z + a.w * b.w;
    }
#pragma unroll
    for (int off = 32; off > 0; off >>= 1)
        acc += __shfl_down(acc, off, 64);

    __shared__ float part[4];
    if (lane == 0) part[wave] = acc;
    __syncthreads();

    if (t == 0) {
        const float y1 = fmaxf(part[0] + part[1] + part[2] + part[3] + b1[row], 0.0f);
        atomicAdd(&ws[row], y1);          // slot was zeroed by kernel 1
        __threadfence();
        const unsigned int old = atomicAdd((unsigned int*)ws + 12, 1u);
        if (old == 11u) {
            float v1[12];
#pragma unroll
            for (int w = 0; w < 12; ++w) v1[w] = atomicAdd(&ws[w], 0.0f);
            float v2[8];
#pragma unroll
            for (int r = 0; r < 8; ++r) {
                float a = b2[r];
#pragma unroll
                for (int k = 0; k < 12; ++k) a += w2[r * 12 + k] * v1[k];
                v2[r] = fmaxf(a, 0.0f);
            }
#pragma unroll
            for (int r = 0; r < 4; ++r) {
                float a = b3[r];
#pragma unroll
                for (int k = 0; k < 8; ++k) a += w3[r * 8 + k] * v2[k];
                out[r] = a;
            }
        }
    }
}

extern "C" void kernel_launch(void* const* d_in, const int* in_sizes, int n_in,
                              void* d_out, int out_size, void* d_ws, size_t ws_size,
                              hipStream_t stream) {
    const float* x    = (const float*)d_in[0];
    const float* h    = (const float*)d_in[1];
    const float* c    = (const float*)d_in[2];
    const float* W_ih = (const float*)d_in[3];
    const float* W_hh = (const float*)d_in[4];
    const float* b_ih = (const float*)d_in[5];
    const float* b_hh = (const float*)d_in[6];
    const float* w1   = (const float*)d_in[7];
    const float* b1   = (const float*)d_in[8];
    const float* w2   = (const float*)d_in[9];
    const float* b2   = (const float*)d_in[10];
    const float* w3   = (const float*)d_in[11];
    const float* b3   = (const float*)d_in[12];
    float* out = (float*)d_out;
    float* ws  = (float*)d_ws;

    lstm_step_kernel<<<H, 256, 0, stream>>>(x, h, c, W_ih, W_hh, b_ih, b_hh, out, ws);
    mlp_head_kernel<<<12, 256, 0, stream>>>(w1, b1, w2, b2, w3, b3, out, ws);
}

// Round 5
// 50.400 us; speedup vs baseline: 13.8484x; 1.0457x over previous
//
#include <hip/hip_runtime.h>
#include <math.h>

#define H 4096

typedef float vf4 __attribute__((ext_vector_type(4)));  // native vec for NT loads

__device__ __forceinline__ float sigmoidf_(float x) {
    return 1.0f / (1.0f + __expf(-x));
}

// Kernel 1: gates = W_ih@x + b_ih + W_hh@h + b_hh ; then c_new/h_new.
// One block per output element j (H blocks). 4 waves: wave g computes the
// dot of W_hh row (g*H + j) with h (4096 elements, float4 loads, wave-wide).
// W_hh is streamed with non-temporal loads (zero reuse) so the shared h
// vector keeps its cache residency.
__global__ __launch_bounds__(256) void lstm_step_kernel(
    const float* __restrict__ x,      // [4]
    const float* __restrict__ h,      // [H]
    const float* __restrict__ c,      // [H]
    const float* __restrict__ W_ih,   // [4H, 4]
    const float* __restrict__ W_hh,   // [4H, H]
    const float* __restrict__ b_ih,   // [4H]
    const float* __restrict__ b_hh,   // [4H]
    float* __restrict__ out)          // [0..4) y, [4..4+H) h_new, [4+H..4+2H) c_new
{
    const int j    = blockIdx.x;           // 0..H-1
    const int wave = threadIdx.x >> 6;     // gate index i,f,g,o
    const int lane = threadIdx.x & 63;
    const int row  = wave * H + j;

    const vf4* __restrict__ Wrow = (const vf4*)(W_hh + (size_t)row * H);
    const vf4* __restrict__ hv   = (const vf4*)h;

    float acc = 0.0f;
#pragma unroll
    for (int it = 0; it < 16; ++it) {
        const int idx = lane + it * 64;    // 0..1023 float4's
        vf4 w4 = __builtin_nontemporal_load(Wrow + idx);
        vf4 h4 = hv[idx];
        acc += w4.x * h4.x + w4.y * h4.y + w4.z * h4.z + w4.w * h4.w;
    }
#pragma unroll
    for (int off = 32; off > 0; off >>= 1)
        acc += __shfl_down(acc, off, 64);

    __shared__ float gate[4];
    if (lane == 0) {
        float g = acc + b_ih[row] + b_hh[row];
        const float4 wi = ((const float4*)W_ih)[row];
        g += wi.x * x[0] + wi.y * x[1] + wi.z * x[2] + wi.w * x[3];
        gate[wave] = g;
    }
    __syncthreads();

    if (threadIdx.x == 0) {
        const float cn = sigmoidf_(gate[1]) * c[j] + sigmoidf_(gate[0]) * tanhf(gate[2]);
        const float hn = sigmoidf_(gate[3]) * tanhf(cn);
        out[4 + j]     = hn;
        out[4 + H + j] = cn;
    }
}

// Kernel 2: MLP head. Single block, 12 waves (768 threads).
// wave w: y1[w] = relu(w1[w] . h_new + b1[w]); then tiny tail layers.
__global__ __launch_bounds__(768) void mlp_head_kernel(
    const float* __restrict__ w1, const float* __restrict__ b1,  // [12,H],[12]
    const float* __restrict__ w2, const float* __restrict__ b2,  // [8,12],[8]
    const float* __restrict__ w3, const float* __restrict__ b3,  // [4,8],[4]
    float* __restrict__ out)
{
    const float* __restrict__ h_new = out + 4;
    const int wave = threadIdx.x >> 6;  // 0..11
    const int lane = threadIdx.x & 63;

    __shared__ float s1[12];
    __shared__ float s2[8];

    const float4* __restrict__ wr = (const float4*)(w1 + (size_t)wave * H);
    const float4* __restrict__ hv = (const float4*)h_new;
    float acc = 0.0f;
#pragma unroll
    for (int it = 0; it < 16; ++it) {
        const int idx = lane + it * 64;
        float4 a = wr[idx];
        float4 b = hv[idx];
        acc += a.x * b.x + a.y * b.y + a.z * b.z + a.w * b.w;
    }
#pragma unroll
    for (int off = 32; off > 0; off >>= 1)
        acc += __shfl_down(acc, off, 64);
    if (lane == 0) s1[wave] = fmaxf(acc + b1[wave], 0.0f);
    __syncthreads();

    if (threadIdx.x < 8) {
        float a = b2[threadIdx.x];
#pragma unroll
        for (int k = 0; k < 12; ++k) a += w2[threadIdx.x * 12 + k] * s1[k];
        s2[threadIdx.x] = fmaxf(a, 0.0f);
    }
    __syncthreads();

    if (threadIdx.x < 4) {
        float a = b3[threadIdx.x];
#pragma unroll
        for (int k = 0; k < 8; ++k) a += w3[threadIdx.x * 8 + k] * s2[k];
        out[threadIdx.x] = a;
    }
}

extern "C" void kernel_launch(void* const* d_in, const int* in_sizes, int n_in,
                              void* d_out, int out_size, void* d_ws, size_t ws_size,
                              hipStream_t stream) {
    const float* x    = (const float*)d_in[0];
    const float* h    = (const float*)d_in[1];
    const float* c    = (const float*)d_in[2];
    const float* W_ih = (const float*)d_in[3];
    const float* W_hh = (const float*)d_in[4];
    const float* b_ih = (const float*)d_in[5];
    const float* b_hh = (const float*)d_in[6];
    const float* w1   = (const float*)d_in[7];
    const float* b1   = (const float*)d_in[8];
    const float* w2   = (const float*)d_in[9];
    const float* b2   = (const float*)d_in[10];
    const float* w3   = (const float*)d_in[11];
    const float* b3   = (const float*)d_in[12];
    float* out = (float*)d_out;

    lstm_step_kernel<<<H, 256, 0, stream>>>(x, h, c, W_ih, W_hh, b_ih, b_hh, out);
    mlp_head_kernel<<<1, 768, 0, stream>>>(w1, b1, w2, b2, w3, b3, out);
}

// Round 6
// 49.742 us; speedup vs baseline: 14.0315x; 1.0132x over previous
//
#include <hip/hip_runtime.h>
#include <math.h>

#define H 4096

typedef float vf4 __attribute__((ext_vector_type(4)));  // native vec for NT loads

__device__ __forceinline__ float sigmoidf_(float x) {
    return 1.0f / (1.0f + __expf(-x));
}

// Kernel 1: gates = W_ih@x + b_ih + W_hh@h + b_hh ; then c_new/h_new.
// One block per output element j (H blocks). 4 waves: wave g computes the
// dot of W_hh row (g*H + j) with h.
//
// L3 capacity partition: W_hh = 268 MB vs 256 MB Infinity Cache -> pure
// streaming LRU-thrashes to ~0% hit across graph replays. Gate-o's chunk
// (rows 3H..4H, 64 MB) is loaded non-temporal so it should not displace the
// other 192 MB, which then stays L3-resident across replays. Steady state:
// 192 MB L3-hit + 64 MB HBM-stream per replay.
__global__ __launch_bounds__(256) void lstm_step_kernel(
    const float* __restrict__ x,      // [4]
    const float* __restrict__ h,      // [H]
    const float* __restrict__ c,      // [H]
    const float* __restrict__ W_ih,   // [4H, 4]
    const float* __restrict__ W_hh,   // [4H, H]
    const float* __restrict__ b_ih,   // [4H]
    const float* __restrict__ b_hh,   // [4H]
    float* __restrict__ out)          // [0..4) y, [4..4+H) h_new, [4+H..4+2H) c_new
{
    const int j    = blockIdx.x;           // 0..H-1
    const int wave = threadIdx.x >> 6;     // gate index i,f,g,o
    const int lane = threadIdx.x & 63;
    const int row  = wave * H + j;

    const vf4* __restrict__ Wrow = (const vf4*)(W_hh + (size_t)row * H);
    const vf4* __restrict__ hv   = (const vf4*)h;

    float acc = 0.0f;
    if (wave == 3) {
        // streamed chunk: bypass cache retention
#pragma unroll
        for (int it = 0; it < 16; ++it) {
            const int idx = lane + it * 64;    // 0..1023 float4's
            vf4 w4 = __builtin_nontemporal_load(Wrow + idx);
            vf4 h4 = hv[idx];
            acc += w4.x * h4.x + w4.y * h4.y + w4.z * h4.z + w4.w * h4.w;
        }
    } else {
        // resident chunk: normal loads, should stay in Infinity Cache
#pragma unroll
        for (int it = 0; it < 16; ++it) {
            const int idx = lane + it * 64;
            vf4 w4 = Wrow[idx];
            vf4 h4 = hv[idx];
            acc += w4.x * h4.x + w4.y * h4.y + w4.z * h4.z + w4.w * h4.w;
        }
    }
#pragma unroll
    for (int off = 32; off > 0; off >>= 1)
        acc += __shfl_down(acc, off, 64);

    __shared__ float gate[4];
    if (lane == 0) {
        float g = acc + b_ih[row] + b_hh[row];
        const float4 wi = ((const float4*)W_ih)[row];
        g += wi.x * x[0] + wi.y * x[1] + wi.z * x[2] + wi.w * x[3];
        gate[wave] = g;
    }
    __syncthreads();

    if (threadIdx.x == 0) {
        const float cn = sigmoidf_(gate[1]) * c[j] + sigmoidf_(gate[0]) * tanhf(gate[2]);
        const float hn = sigmoidf_(gate[3]) * tanhf(cn);
        out[4 + j]     = hn;
        out[4 + H + j] = cn;
    }
}

// Kernel 2: MLP head. Single block, 12 waves (768 threads).
__global__ __launch_bounds__(768) void mlp_head_kernel(
    const float* __restrict__ w1, const float* __restrict__ b1,  // [12,H],[12]
    const float* __restrict__ w2, const float* __restrict__ b2,  // [8,12],[8]
    const float* __restrict__ w3, const float* __restrict__ b3,  // [4,8],[4]
    float* __restrict__ out)
{
    const float* __restrict__ h_new = out + 4;
    const int wave = threadIdx.x >> 6;  // 0..11
    const int lane = threadIdx.x & 63;

    __shared__ float s1[12];
    __shared__ float s2[8];

    const float4* __restrict__ wr = (const float4*)(w1 + (size_t)wave * H);
    const float4* __restrict__ hv = (const float4*)h_new;
    float acc = 0.0f;
#pragma unroll
    for (int it = 0; it < 16; ++it) {
        const int idx = lane + it * 64;
        float4 a = wr[idx];
        float4 b = hv[idx];
        acc += a.x * b.x + a.y * b.y + a.z * b.z + a.w * b.w;
    }
#pragma unroll
    for (int off = 32; off > 0; off >>= 1)
        acc += __shfl_down(acc, off, 64);
    if (lane == 0) s1[wave] = fmaxf(acc + b1[wave], 0.0f);
    __syncthreads();

    if (threadIdx.x < 8) {
        float a = b2[threadIdx.x];
#pragma unroll
        for (int k = 0; k < 12; ++k) a += w2[threadIdx.x * 12 + k] * s1[k];
        s2[threadIdx.x] = fmaxf(a, 0.0f);
    }
    __syncthreads();

    if (threadIdx.x < 4) {
        float a = b3[threadIdx.x];
#pragma unroll
        for (int k = 0; k < 8; ++k) a += w3[threadIdx.x * 8 + k] * s2[k];
        out[threadIdx.x] = a;
    }
}

extern "C" void kernel_launch(void* const* d_in, const int* in_sizes, int n_in,
                              void* d_out, int out_size, void* d_ws, size_t ws_size,
                              hipStream_t stream) {
    const float* x    = (const float*)d_in[0];
    const float* h    = (const float*)d_in[1];
    const float* c    = (const float*)d_in[2];
    const float* W_ih = (const float*)d_in[3];
    const float* W_hh = (const float*)d_in[4];
    const float* b_ih = (const float*)d_in[5];
    const float* b_hh = (const float*)d_in[6];
    const float* w1   = (const float*)d_in[7];
    const float* b1   = (const float*)d_in[8];
    const float* w2   = (const float*)d_in[9];
    const float* b2   = (const float*)d_in[10];
    const float* w3   = (const float*)d_in[11];
    const float* b3   = (const float*)d_in[12];
    float* out = (float*)d_out;

    lstm_step_kernel<<<H, 256, 0, stream>>>(x, h, c, W_ih, W_hh, b_ih, b_hh, out);
    mlp_head_kernel<<<1, 768, 0, stream>>>(w1, b1, w2, b2, w3, b3, out);
}

// Round 7
// 49.567 us; speedup vs baseline: 14.0810x; 1.0035x over previous
//
#include <hip/hip_runtime.h>
#include <math.h>

#define H 4096

typedef float vf4 __attribute__((ext_vector_type(4)));  // native vec type

__device__ __forceinline__ float sigmoidf_(float x) {
    return 1.0f / (1.0f + __expf(-x));
}

// Kernel 1: gates = W_ih@x + b_ih + W_hh@h + b_hh ; then c_new/h_new.
// One block per output element j (H blocks). 4 waves: wave g computes the
// dot of W_hh row (g*H + j) with h.
//
// L3 capacity partition, attempt 2: round 6 showed `nt` alone does not gate
// MALL allocation. Here gate-o's 64 MB chunk is read with system-scope
// non-temporal loads (inline asm `global_load_dwordx4 ... sc0 sc1 nt`) —
// the strongest no-allocate encoding gfx950 has. If MALL then skips those
// lines, the other 204 MB stays L3-resident across graph replays.
__global__ __launch_bounds__(256) void lstm_step_kernel(
    const float* __restrict__ x,      // [4]
    const float* __restrict__ h,      // [H]
    const float* __restrict__ c,      // [H]
    const float* __restrict__ W_ih,   // [4H, 4]
    const float* __restrict__ W_hh,   // [4H, H]
    const float* __restrict__ b_ih,   // [4H]
    const float* __restrict__ b_hh,   // [4H]
    float* __restrict__ out)          // [0..4) y, [4..4+H) h_new, [4+H..4+2H) c_new
{
    const int j    = blockIdx.x;           // 0..H-1
    const int wave = threadIdx.x >> 6;     // gate index i,f,g,o
    const int lane = threadIdx.x & 63;
    const int row  = wave * H + j;

    const vf4* __restrict__ Wrow = (const vf4*)(W_hh + (size_t)row * H);
    const vf4* __restrict__ hv   = (const vf4*)h;

    float acc = 0.0f;
    if (wave == 3) {
        // streamed chunk: system-scope + NT loads, batches of 4 in flight
#pragma unroll
        for (int it = 0; it < 16; it += 4) {
            vf4 w0, w1, w2, w3;
            const vf4* p0 = Wrow + (lane + (it + 0) * 64);
            const vf4* p1 = Wrow + (lane + (it + 1) * 64);
            const vf4* p2 = Wrow + (lane + (it + 2) * 64);
            const vf4* p3 = Wrow + (lane + (it + 3) * 64);
            asm volatile("global_load_dwordx4 %0, %1, off sc0 sc1 nt" : "=&v"(w0) : "v"(p0));
            asm volatile("global_load_dwordx4 %0, %1, off sc0 sc1 nt" : "=&v"(w1) : "v"(p1));
            asm volatile("global_load_dwordx4 %0, %1, off sc0 sc1 nt" : "=&v"(w2) : "v"(p2));
            asm volatile("global_load_dwordx4 %0, %1, off sc0 sc1 nt" : "=&v"(w3) : "v"(p3));
            vf4 h0 = hv[lane + (it + 0) * 64];
            vf4 h1 = hv[lane + (it + 1) * 64];
            vf4 h2 = hv[lane + (it + 2) * 64];
            vf4 h3 = hv[lane + (it + 3) * 64];
            asm volatile("s_waitcnt vmcnt(0)" ::: "memory");
            __builtin_amdgcn_sched_barrier(0);
            acc += w0.x * h0.x + w0.y * h0.y + w0.z * h0.z + w0.w * h0.w;
            acc += w1.x * h1.x + w1.y * h1.y + w1.z * h1.z + w1.w * h1.w;
            acc += w2.x * h2.x + w2.y * h2.y + w2.z * h2.z + w2.w * h2.w;
            acc += w3.x * h3.x + w3.y * h3.y + w3.z * h3.z + w3.w * h3.w;
        }
    } else {
        // resident chunk: normal loads, should stay in Infinity Cache
#pragma unroll
        for (int it = 0; it < 16; ++it) {
            const int idx = lane + it * 64;
            vf4 w4 = Wrow[idx];
            vf4 h4 = hv[idx];
            acc += w4.x * h4.x + w4.y * h4.y + w4.z * h4.z + w4.w * h4.w;
        }
    }
#pragma unroll
    for (int off = 32; off > 0; off >>= 1)
        acc += __shfl_down(acc, off, 64);

    __shared__ float gate[4];
    if (lane == 0) {
        float g = acc + b_ih[row] + b_hh[row];
        const float4 wi = ((const float4*)W_ih)[row];
        g += wi.x * x[0] + wi.y * x[1] + wi.z * x[2] + wi.w * x[3];
        gate[wave] = g;
    }
    __syncthreads();

    if (threadIdx.x == 0) {
        const float cn = sigmoidf_(gate[1]) * c[j] + sigmoidf_(gate[0]) * tanhf(gate[2]);
        const float hn = sigmoidf_(gate[3]) * tanhf(cn);
        out[4 + j]     = hn;
        out[4 + H + j] = cn;
    }
}

// Kernel 2: MLP head. Single block, 12 waves (768 threads).
__global__ __launch_bounds__(768) void mlp_head_kernel(
    const float* __restrict__ w1, const float* __restrict__ b1,  // [12,H],[12]
    const float* __restrict__ w2, const float* __restrict__ b2,  // [8,12],[8]
    const float* __restrict__ w3, const float* __restrict__ b3,  // [4,8],[4]
    float* __restrict__ out)
{
    const float* __restrict__ h_new = out + 4;
    const int wave = threadIdx.x >> 6;  // 0..11
    const int lane = threadIdx.x & 63;

    __shared__ float s1[12];
    __shared__ float s2[8];

    const float4* __restrict__ wr = (const float4*)(w1 + (size_t)wave * H);
    const float4* __restrict__ hv = (const float4*)h_new;
    float acc = 0.0f;
#pragma unroll
    for (int it = 0; it < 16; ++it) {
        const int idx = lane + it * 64;
        float4 a = wr[idx];
        float4 b = hv[idx];
        acc += a.x * b.x + a.y * b.y + a.z * b.z + a.w * b.w;
    }
#pragma unroll
    for (int off = 32; off > 0; off >>= 1)
        acc += __shfl_down(acc, off, 64);
    if (lane == 0) s1[wave] = fmaxf(acc + b1[wave], 0.0f);
    __syncthreads();

    if (threadIdx.x < 8) {
        float a = b2[threadIdx.x];
#pragma unroll
        for (int k = 0; k < 12; ++k) a += w2[threadIdx.x * 12 + k] * s1[k];
        s2[threadIdx.x] = fmaxf(a, 0.0f);
    }
    __syncthreads();

    if (threadIdx.x < 4) {
        float a = b3[threadIdx.x];
#pragma unroll
        for (int k = 0; k < 8; ++k) a += w3[threadIdx.x * 8 + k] * s2[k];
        out[threadIdx.x] = a;
    }
}

extern "C" void kernel_launch(void* const* d_in, const int* in_sizes, int n_in,
                              void* d_out, int out_size, void* d_ws, size_t ws_size,
                              hipStream_t stream) {
    const float* x    = (const float*)d_in[0];
    const float* h    = (const float*)d_in[1];
    const float* c    = (const float*)d_in[2];
    const float* W_ih = (const float*)d_in[3];
    const float* W_hh = (const float*)d_in[4];
    const float* b_ih = (const float*)d_in[5];
    const float* b_hh = (const float*)d_in[6];
    const float* w1   = (const float*)d_in[7];
    const float* b1   = (const float*)d_in[8];
    const float* w2   = (const float*)d_in[9];
    const float* b2   = (const float*)d_in[10];
    const float* w3   = (const float*)d_in[11];
    const float* b3   = (const float*)d_in[12];
    float* out = (float*)d_out;

    lstm_step_kernel<<<H, 256, 0, stream>>>(x, h, c, W_ih, W_hh, b_ih, b_hh, out);
    mlp_head_kernel<<<1, 768, 0, stream>>>(w1, b1, w2, b2, w3, b3, out);
}